// Round 1
// baseline (1384.978 us; speedup 1.0000x reference)
//
#include <hip/hip_runtime.h>
#include <math.h>

#define BB 2048          // batch
#define FD 256           // num_features
#define HD 128           // hidden
#define FF 65536         // F*F
#define TK 15            // top-k
#define NCH 8            // N-chunks for the big GEMM (chunk -> XCD via blockIdx%8)
#define MT 8             // rows per block in k2
#define CAP2 128         // per-wave per-row candidate buffer
#define CPC (FF / NCH)   // 8192 cols per chunk
#define WCOLS (CPC / 4)  // 2048 cols per wave
#define NIT (WCOLS / 256)// 8 iterations per wave
#define NEG_INF (-3.4e38f)
#define EPSF 1e-8f

// ---------------------------------------------------------------------------
// Kernel 1: front-end MLPs. 4 rows per block.
//   h_rs = relu(x@rs_w1+rs_b1)            -> ws
//   tf   = relu(x@ft_w1+ft_b1)@ft_w2+ft_b2 -> ws
//   op_w = softmax(relu(x@os_w1+os_b1)@os_w2+os_b2) -> ws
// ---------------------------------------------------------------------------
__global__ __launch_bounds__(256) void k1_front(
    const float* __restrict__ x,
    const float* __restrict__ rs_w1, const float* __restrict__ rs_b1,
    const float* __restrict__ os_w1, const float* __restrict__ os_b1,
    const float* __restrict__ os_w2, const float* __restrict__ os_b2,
    const float* __restrict__ ft_w1, const float* __restrict__ ft_b1,
    const float* __restrict__ ft_w2, const float* __restrict__ ft_b2,
    float* __restrict__ hrs, float* __restrict__ tf, float* __restrict__ opw)
{
  __shared__ float xs[4 * FD];
  __shared__ float hft[4][HD];
  __shared__ float hos[4][HD];
  __shared__ float lg[4][4];
  const int tid = threadIdx.x;
  const int r0  = blockIdx.x * 4;

  for (int i = tid; i < 4 * FD; i += 256) xs[i] = x[(size_t)r0 * FD + i];
  __syncthreads();

  {  // hidden layers: thread (h, half) does 2 rows x 3 nets
    const int h    = tid & (HD - 1);
    const int half = tid >> 7;
    const int ra = 2 * half, rb = ra + 1;
    float a0=0.f,a1=0.f,b0=0.f,b1=0.f,c0=0.f,c1=0.f;
    for (int f = 0; f < FD; ++f) {
      const float wr = rs_w1[f*HD+h], wf = ft_w1[f*HD+h], wo = os_w1[f*HD+h];
      const float x0 = xs[ra*FD+f],   x1 = xs[rb*FD+f];
      a0 = fmaf(x0,wr,a0); a1 = fmaf(x1,wr,a1);
      b0 = fmaf(x0,wf,b0); b1 = fmaf(x1,wf,b1);
      c0 = fmaf(x0,wo,c0); c1 = fmaf(x1,wo,c1);
    }
    const float brs = rs_b1[h], bft = ft_b1[h], bos = os_b1[h];
    hrs[(size_t)(r0+ra)*HD + h] = fmaxf(a0 + brs, 0.f);
    hrs[(size_t)(r0+rb)*HD + h] = fmaxf(a1 + brs, 0.f);
    hft[ra][h] = fmaxf(b0 + bft, 0.f);
    hft[rb][h] = fmaxf(b1 + bft, 0.f);
    hos[ra][h] = fmaxf(c0 + bos, 0.f);
    hos[rb][h] = fmaxf(c1 + bos, 0.f);
  }
  __syncthreads();

  {  // tf: thread = column c, 4 rows
    const int c = tid;
    const float bb = ft_b2[c];
    float t0=bb,t1=bb,t2=bb,t3=bb;
    for (int h = 0; h < HD; ++h) {
      const float w = ft_w2[h*FD + c];
      t0 = fmaf(hft[0][h],w,t0); t1 = fmaf(hft[1][h],w,t1);
      t2 = fmaf(hft[2][h],w,t2); t3 = fmaf(hft[3][h],w,t3);
    }
    tf[(size_t)(r0+0)*FD+c]=t0; tf[(size_t)(r0+1)*FD+c]=t1;
    tf[(size_t)(r0+2)*FD+c]=t2; tf[(size_t)(r0+3)*FD+c]=t3;
  }

  if (tid < 16) {  // op logits
    const int r = tid >> 2, o = tid & 3;
    float a = os_b2[o];
    for (int h = 0; h < HD; ++h) a = fmaf(hos[r][h], os_w2[h*4 + o], a);
    lg[r][o] = a;
  }
  __syncthreads();
  if (tid < 16) {  // softmax over 4
    const int r = tid >> 2, o = tid & 3;
    const float m = fmaxf(fmaxf(lg[r][0],lg[r][1]), fmaxf(lg[r][2],lg[r][3]));
    const float e = __expf(lg[r][o]-m);
    const float s = __expf(lg[r][0]-m)+__expf(lg[r][1]-m)+__expf(lg[r][2]-m)+__expf(lg[r][3]-m);
    opw[(size_t)(r0+r)*4+o] = e/s;
  }
}

// ---------------------------------------------------------------------------
// Kernel 2: fused sel-GEMM + sigmoid + entropy + per-chunk top-15.
// Grid: (BB/MT)*NCH blocks of 256. chunk = blockIdx%8 -> pins chunk to an XCD.
// Each wave: 8 rows x 2048 cols, 8 iterations of 256 cols (4/thread).
// Top-k: rising LDS threshold filters logits into per-row LDS buffers;
// 8 lanes/wave keep register-resident sorted-15 (value desc, index asc).
// ---------------------------------------------------------------------------
__global__ __launch_bounds__(256) void k2_sel(
    const float* __restrict__ W2, const float* __restrict__ b2,
    const float* __restrict__ hrs,
    float* __restrict__ cand_v, int* __restrict__ cand_i,
    float* __restrict__ ent_part)
{
  __shared__ float hs[MT * HD];           // 4KB
  __shared__ float bufv[4][MT][CAP2];     // 16KB
  __shared__ int   bufi[4][MT][CAP2];     // 16KB
  __shared__ float thr[4][MT];
  __shared__ int   cnt[4][MT];
  __shared__ int   dropf[4];
  __shared__ float entred[4];

  const int tid   = threadIdx.x;
  const int wave  = tid >> 6;
  const int lane  = tid & 63;
  const int bx    = blockIdx.x;
  const int chunk = bx & (NCH - 1);
  const int mb    = bx >> 3;
  const int r0    = mb * MT;

  for (int i = tid; i < MT * HD; i += 256) hs[i] = hrs[(size_t)r0 * HD + i];
  if (lane < MT) { thr[wave][lane] = NEG_INF; cnt[wave][lane] = 0; }
  if (lane == 0) dropf[wave] = 0;
  __syncthreads();

  float kv[TK]; int ki[TK];
#pragma unroll
  for (int p = 0; p < TK; ++p) { kv[p] = NEG_INF; ki[p] = 0x7fffffff; }

  float ent = 0.f;
  const int wbase = chunk * CPC + wave * WCOLS;

  for (int it = 0; it < NIT; ++it) {
    const int c0 = wbase + it * 256 + lane * 4;
    const float* wp = W2 + c0;
    float acc[MT][4];
#pragma unroll
    for (int r = 0; r < MT; ++r) { acc[r][0]=0.f; acc[r][1]=0.f; acc[r][2]=0.f; acc[r][3]=0.f; }

    for (int h = 0; h < HD; h += 4) {
      const float4 q0 = *(const float4*)(wp + (size_t)(h+0) * FF);
      const float4 q1 = *(const float4*)(wp + (size_t)(h+1) * FF);
      const float4 q2 = *(const float4*)(wp + (size_t)(h+2) * FF);
      const float4 q3 = *(const float4*)(wp + (size_t)(h+3) * FF);
#pragma unroll
      for (int r = 0; r < MT; ++r) {
        const float4 a = *(const float4*)&hs[r * HD + h];
        acc[r][0]=fmaf(a.x,q0.x,acc[r][0]); acc[r][0]=fmaf(a.y,q1.x,acc[r][0]);
        acc[r][0]=fmaf(a.z,q2.x,acc[r][0]); acc[r][0]=fmaf(a.w,q3.x,acc[r][0]);
        acc[r][1]=fmaf(a.x,q0.y,acc[r][1]); acc[r][1]=fmaf(a.y,q1.y,acc[r][1]);
        acc[r][1]=fmaf(a.z,q2.y,acc[r][1]); acc[r][1]=fmaf(a.w,q3.y,acc[r][1]);
        acc[r][2]=fmaf(a.x,q0.z,acc[r][2]); acc[r][2]=fmaf(a.y,q1.z,acc[r][2]);
        acc[r][2]=fmaf(a.z,q2.z,acc[r][2]); acc[r][2]=fmaf(a.w,q3.z,acc[r][2]);
        acc[r][3]=fmaf(a.x,q0.w,acc[r][3]); acc[r][3]=fmaf(a.y,q1.w,acc[r][3]);
        acc[r][3]=fmaf(a.z,q2.w,acc[r][3]); acc[r][3]=fmaf(a.w,q3.w,acc[r][3]);
      }
    }
    const float4 bb = *(const float4*)(b2 + c0);

    // entropy on the fly (sigmoid monotone -> top-k stays on logits)
#pragma unroll
    for (int r = 0; r < MT; ++r) {
      const float z0=acc[r][0]+bb.x, z1=acc[r][1]+bb.y, z2=acc[r][2]+bb.z, z3=acc[r][3]+bb.w;
      float s;
      s = __builtin_amdgcn_rcpf(1.f + __expf(-z0)); ent = fmaf(s, __logf(s + EPSF), ent);
      s = __builtin_amdgcn_rcpf(1.f + __expf(-z1)); ent = fmaf(s, __logf(s + EPSF), ent);
      s = __builtin_amdgcn_rcpf(1.f + __expf(-z2)); ent = fmaf(s, __logf(s + EPSF), ent);
      s = __builtin_amdgcn_rcpf(1.f + __expf(-z3)); ent = fmaf(s, __logf(s + EPSF), ent);
    }

    // top-k append passes with rising threshold (wave-local, no block barrier)
    unsigned int done = 0;
    for (;;) {
      float tl[MT];
#pragma unroll
      for (int r = 0; r < MT; ++r) tl[r] = thr[wave][r];
#pragma unroll
      for (int r = 0; r < MT; ++r) {
        const float zz0=acc[r][0]+bb.x, zz1=acc[r][1]+bb.y, zz2=acc[r][2]+bb.z, zz3=acc[r][3]+bb.w;
        const float zz[4] = {zz0, zz1, zz2, zz3};
#pragma unroll
        for (int j = 0; j < 4; ++j) {
          const unsigned bit = 1u << (r * 4 + j);
          if (!(done & bit)) {
            if (zz[j] >= tl[r]) {
              const int pos = atomicAdd(&cnt[wave][r], 1);
              if (pos < CAP2) { bufv[wave][r][pos] = zz[j]; bufi[wave][r][pos] = c0 + j; done |= bit; }
              else dropf[wave] = 1;
            } else done |= bit;   // threshold only rises -> gone forever
          }
        }
      }
      __threadfence_block();
      if (lane < MT) {           // lane r flushes row r into its register list
        const int r = lane;
        const int m = min(cnt[wave][r], CAP2);
        for (int q = 0; q < m; ++q) {
          const float v = bufv[wave][r][q]; const int ix = bufi[wave][r][q];
          if (v > kv[TK-1] || (v == kv[TK-1] && ix < ki[TK-1])) {
            float cv = v; int ci = ix;
#pragma unroll
            for (int p = 0; p < TK; ++p) {
              const bool bet = (cv > kv[p]) || (cv == kv[p] && ci < ki[p]);
              const float tv = kv[p]; const int ti = ki[p];
              if (bet) { kv[p] = cv; ki[p] = ci; cv = tv; ci = ti; }
            }
          }
        }
        cnt[wave][r] = 0;
        thr[wave][r] = kv[TK-1];
      }
      __threadfence_block();
      if (dropf[wave] == 0) break;
      if (lane == 0) dropf[wave] = 0;
      __threadfence_block();
    }
  }

  // dump per-wave sorted lists (reuse buffers), then merge 4 waves per row
  if (lane < MT) {
#pragma unroll
    for (int p = 0; p < TK; ++p) { bufv[wave][lane][p] = kv[p]; bufi[wave][lane][p] = ki[p]; }
  }
  __syncthreads();
  if (tid < MT) {  // thread r: 4-way merge of sorted lists, emit sigmoid + idx
    int p0=0,p1=0,p2=0,p3=0;
    for (int round = 0; round < TK; ++round) {
      float bv = NEG_INF; int bi = 0x7fffffff; int bw = 0;
      { const float v=bufv[0][tid][p0]; const int ix=bufi[0][tid][p0];
        if (p0<TK && (v>bv||(v==bv&&ix<bi))) {bv=v;bi=ix;bw=0;} }
      { const float v=bufv[1][tid][p1]; const int ix=bufi[1][tid][p1];
        if (p1<TK && (v>bv||(v==bv&&ix<bi))) {bv=v;bi=ix;bw=1;} }
      { const float v=bufv[2][tid][p2]; const int ix=bufi[2][tid][p2];
        if (p2<TK && (v>bv||(v==bv&&ix<bi))) {bv=v;bi=ix;bw=2;} }
      { const float v=bufv[3][tid][p3]; const int ix=bufi[3][tid][p3];
        if (p3<TK && (v>bv||(v==bv&&ix<bi))) {bv=v;bi=ix;bw=3;} }
      if (bw==0) ++p0; else if (bw==1) ++p1; else if (bw==2) ++p2; else ++p3;
      const float sel = 1.0f / (1.0f + __expf(-bv));
      const size_t o = ((size_t)(r0 + tid) * NCH + chunk) * TK + round;
      cand_v[o] = sel; cand_i[o] = bi;
    }
  }

  // entropy block reduction -> one partial per block
#pragma unroll
  for (int off = 32; off >= 1; off >>= 1) ent += __shfl_down(ent, off);
  if (lane == 0) entred[wave] = ent;
  __syncthreads();
  if (tid == 0) ent_part[bx] = entred[0] + entred[1] + entred[2] + entred[3];
}

// ---------------------------------------------------------------------------
// Kernel 3: merge 8 chunk-lists per row -> global top-15, compute ratio ops.
// One wave per row (4 rows/block).
// ---------------------------------------------------------------------------
__global__ __launch_bounds__(256) void k3_merge(
    const float* __restrict__ cand_v, const int* __restrict__ cand_i,
    const float* __restrict__ tf, const float* __restrict__ opw,
    float* __restrict__ out_rt, float* __restrict__ pi_part, float* __restrict__ mag_part)
{
  __shared__ float s_pi[4][TK];
  __shared__ float s_mag[4][TK];
  const int tid  = threadIdx.x;
  const int wave = tid >> 6, lane = tid & 63;
  const int row  = blockIdx.x * 4 + wave;
  const float* lv = cand_v + ((size_t)row * NCH + (lane & 7)) * TK;
  const int*   li = cand_i + ((size_t)row * NCH + (lane & 7)) * TK;
  int p = 0;
  float rv = 0.f; int ri = 0;

  for (int round = 0; round < TK; ++round) {
    float hv = NEG_INF; int hi = 0x7fffffff;
    if (lane < NCH && p < TK) { hv = lv[p]; hi = li[p]; }
    float bv = hv; int bi = hi;
#pragma unroll
    for (int off = 8; off >= 1; off >>= 1) {
      const float ov = __shfl_xor(bv, off);
      const int   oi = __shfl_xor(bi, off);
      if (ov > bv || (ov == bv && oi < bi)) { bv = ov; bi = oi; }
    }
    if (lane < NCH && p < TK && hi == bi) ++p;   // unique winner advances
    if (lane == round) { rv = bv; ri = bi; }
  }

  if (lane < TK) {
    const int j = ri, ii = j >> 8, jj = j & 255;
    const float fi = tf[(size_t)row * FD + ii];
    const float fj = tf[(size_t)row * FD + jj];
    const float* w = opw + (size_t)row * 4;
    const float ratio = fi / (fabsf(fj) + EPSF);
    const float lr    = logf(fabsf(fi) + EPSF) - logf(fabsf(fj) + EPSF);
    const float rt    = ratio * w[0] + lr * w[1] + (fi - fj) * w[2] + fi * fj * w[3];
    out_rt[(size_t)row * TK + lane] = rt;
    s_pi[wave][lane]  = rv;
    s_mag[wave][lane] = fabsf(rt);
  }
  __syncthreads();
  if (tid < TK) {
    pi_part[(size_t)blockIdx.x * TK + tid]  = s_pi[0][tid]+s_pi[1][tid]+s_pi[2][tid]+s_pi[3][tid];
    mag_part[(size_t)blockIdx.x * TK + tid] = s_mag[0][tid]+s_mag[1][tid]+s_mag[2][tid]+s_mag[3][tid];
  }
}

// ---------------------------------------------------------------------------
// Kernel 4: deterministic final reductions -> means + entropy.
// out layout: [0..30719] rt, [+0..14] pair_imp, [+15..18] op_prefs,
//             [+19..33] ratio_mags, [+34] entropy
// ---------------------------------------------------------------------------
__global__ __launch_bounds__(256) void k4_final(
    const float* __restrict__ pi_part, const float* __restrict__ mag_part,
    const float* __restrict__ opw, const float* __restrict__ ent_part,
    float* __restrict__ out)
{
  __shared__ float red[256];
  const int tid = threadIdx.x;
  const int NB3 = BB / 4;          // 512
  const int base = BB * TK;        // 30720

  {  // pair_importances
    const int r = tid & 15, seg = tid >> 4;
    float s = 0.f;
    if (r < TK) for (int q = seg; q < NB3; q += 16) s += pi_part[(size_t)q * TK + r];
    red[tid] = s; __syncthreads();
    if (tid < TK) { float t = 0.f; for (int g = 0; g < 16; ++g) t += red[g*16 + tid];
      out[base + tid] = t / (float)BB; }
    __syncthreads();
  }
  {  // ratio_mags
    const int r = tid & 15, seg = tid >> 4;
    float s = 0.f;
    if (r < TK) for (int q = seg; q < NB3; q += 16) s += mag_part[(size_t)q * TK + r];
    red[tid] = s; __syncthreads();
    if (tid < TK) { float t = 0.f; for (int g = 0; g < 16; ++g) t += red[g*16 + tid];
      out[base + 19 + tid] = t / (float)BB; }
    __syncthreads();
  }
  {  // op_prefs
    const int o = tid & 3, seg = tid >> 2;
    float s = 0.f;
    for (int q = seg; q < BB; q += 64) s += opw[(size_t)q * 4 + o];
    red[tid] = s; __syncthreads();
    if (tid < 4) { float t = 0.f; for (int g = 0; g < 64; ++g) t += red[g*4 + tid];
      out[base + 15 + tid] = t / (float)BB; }
    __syncthreads();
  }
  {  // entropy
    float s = 0.f;
    const int NE = (BB / MT) * NCH;   // 2048
    for (int q = tid; q < NE; q += 256) s += ent_part[q];
    red[tid] = s; __syncthreads();
    for (int off = 128; off >= 1; off >>= 1) {
      if (tid < off) red[tid] += red[tid + off];
      __syncthreads();
    }
    if (tid == 0) out[base + 34] = -red[0] / (float)BB;
  }
}

// ---------------------------------------------------------------------------
extern "C" void kernel_launch(void* const* d_in, const int* in_sizes, int n_in,
                              void* d_out, int out_size, void* d_ws, size_t ws_size,
                              hipStream_t stream) {
  (void)in_sizes; (void)n_in; (void)out_size; (void)ws_size;
  const float* x     = (const float*)d_in[0];
  const float* rs_w1 = (const float*)d_in[1];
  const float* rs_b1 = (const float*)d_in[2];
  const float* rs_w2 = (const float*)d_in[3];
  const float* rs_b2 = (const float*)d_in[4];
  const float* os_w1 = (const float*)d_in[5];
  const float* os_b1 = (const float*)d_in[6];
  const float* os_w2 = (const float*)d_in[7];
  const float* os_b2 = (const float*)d_in[8];
  const float* ft_w1 = (const float*)d_in[9];
  const float* ft_b1 = (const float*)d_in[10];
  const float* ft_w2 = (const float*)d_in[11];
  const float* ft_b2 = (const float*)d_in[12];
  float* out = (float*)d_out;

  float* ws      = (float*)d_ws;
  float* hrs     = ws;                         // BB*HD
  float* tf      = hrs + (size_t)BB * HD;      // BB*FD
  float* opw     = tf + (size_t)BB * FD;       // BB*4
  float* cand_v  = opw + (size_t)BB * 4;       // BB*NCH*TK
  int*   cand_i  = (int*)(cand_v + (size_t)BB * NCH * TK);
  float* ent_part= (float*)(cand_i + (size_t)BB * NCH * TK);  // (BB/MT)*NCH
  float* pi_part = ent_part + (BB / MT) * NCH; // (BB/4)*TK
  float* mag_part= pi_part + (BB / 4) * TK;    // (BB/4)*TK

  hipLaunchKernelGGL(k1_front, dim3(BB/4), dim3(256), 0, stream,
                     x, rs_w1, rs_b1, os_w1, os_b1, os_w2, os_b2,
                     ft_w1, ft_b1, ft_w2, ft_b2, hrs, tf, opw);
  hipLaunchKernelGGL(k2_sel, dim3((BB/MT)*NCH), dim3(256), 0, stream,
                     rs_w2, rs_b2, hrs, cand_v, cand_i, ent_part);
  hipLaunchKernelGGL(k3_merge, dim3(BB/4), dim3(256), 0, stream,
                     cand_v, cand_i, tf, opw, out, pi_part, mag_part);
  hipLaunchKernelGGL(k4_final, dim3(1), dim3(256), 0, stream,
                     pi_part, mag_part, opw, ent_part, out);
}